// Round 17
// baseline (63.180 us; speedup 1.0000x reference)
//
#include <hip/hip_runtime.h>
#include <hip/hip_bf16.h>

#define WT0 (-0.09375f)
#define WT1 (0.59375f)

// ---------------------------------------------------------------------------
// K1: level-0 loss, tile 128x8, 2 rows x 2 px per thread (PX=2 targets the
// 64-VGPR boundary: R4 measured the PX=2 loss core at exactly 64 VGPR ->
// 8 waves/SIMD). Stage 2x14x136 floats (14.9KB, rows by0-3..by0+10, quad-
// aligned cols bx0-4..) + f1 scratch 2x6x66 (3.1KB) = 18KB LDS -> target
// 8 blocks/CU = 32 waves/CU (vs R16's 16). Emits f1 interior (4x64/img) and
// f2 (2x32/img) like R14-16 so the whole tail stays one kernel.
// ---------------------------------------------------------------------------
__global__ __launch_bounds__(256) void k1_kernel(
    const float* __restrict__ fake, const float* __restrict__ hdr,
    const float* __restrict__ window, const float* __restrict__ RW,
    double* __restrict__ slots,
    float* __restrict__ f1, float* __restrict__ h1,
    float* __restrict__ f2, float* __restrict__ h2)
{
    __shared__ __align__(16) float stg[2][14][136];
    __shared__ float f1b[2][6][66];
    __shared__ float swin[25];
    __shared__ float wred[4];

    const int tid = threadIdx.x;
    const int tx = tid & 63, ty = tid >> 6;
    if (tid < 25) swin[tid] = window[tid];

    const int bx0 = blockIdx.x * 128;
    const int by0 = blockIdx.y * 8;
    const int b   = blockIdx.z;

    const float* Fb = fake + (size_t)b * 512 * 512;
    const float* Hb = hdr  + (size_t)b * 512 * 512;

    // stage 14x136 per image as float4 quads (34 quads/row), zero-padded.
    // Row origin by0-3 (loss needs by0-2..+9; f1 needs by0-3..+10).
    for (int i = tid; i < 2 * 14 * 34; i += 256) {
        const int img = i / 476, j = i % 476;
        const int r = j / 34, c4 = j % 34;
        const int y = by0 - 3 + r, xs = bx0 - 4 + 4 * c4;
        float4 v = make_float4(0.f, 0.f, 0.f, 0.f);
        if ((unsigned)y < 512u && (unsigned)xs < 512u)
            v = *(const float4*)((img ? Hb : Fb) + (size_t)y * 512 + xs);
        *(float4*)&stg[img][r][4 * c4] = v;
    }
    __syncthreads();

    // ---- loss: rows (by0+ty) and (by0+ty+4), 2 px each (cols bx0+2tx..+1) ----
    float vacc = 0.f;
    const size_t ks = (size_t)512 * 512;
#pragma unroll
    for (int rr = 0; rr < 2; ++rr) {
        const int y = by0 + ty + 4 * rr;
        const float* rwp = RW + (size_t)b * 25 * ks + (size_t)y * 512 + (bx0 + 2 * tx);
        float wsum[2] = {0.f, 0.f}, fs[2] = {0.f, 0.f}, hs[2] = {0.f, 0.f};
#pragma unroll
        for (int di = 0; di < 5; ++di) {
            const int srow = ty + 4 * rr + di + 1;   // image row y+di-2, origin by0-3
            // window col = bx0+2tx+p+dj-2 -> stage col 2tx+2+(p+dj), p+dj in [0,6]
            float f7[8], h7[8];
            const int ro = 2 * tx + 2;
#pragma unroll
            for (int q2 = 0; q2 < 4; ++q2) {
                const float2 af = *(const float2*)&stg[0][srow][ro + 2 * q2];
                f7[2 * q2] = af.x; f7[2 * q2 + 1] = af.y;
                const float2 ah = *(const float2*)&stg[1][srow][ro + 2 * q2];
                h7[2 * q2] = ah.x; h7[2 * q2 + 1] = ah.y;
            }
#pragma unroll
            for (int dj = 0; dj < 5; ++dj) {
                const int k = di * 5 + dj;
                const float2 rv = *(const float2*)(rwp + (size_t)k * ks);
                const float w0 = swin[k] * rv.x, w1 = swin[k] * rv.y;
                wsum[0] += w0; wsum[1] += w1;
                fs[0] = fmaf(w0, f7[dj + 0], fs[0]);
                fs[1] = fmaf(w1, f7[dj + 1], fs[1]);
                hs[0] = fmaf(w0, h7[dj + 0], hs[0]);
                hs[1] = fmaf(w1, h7[dj + 1], hs[1]);
            }
        }
        const float d0 = (fs[0] - hs[0]) / wsum[0];
        const float d1 = (fs[1] - hs[1]) / wsum[1];
        vacc = fmaf(d0, d0, fmaf(d1, d1, vacc));
    }
#pragma unroll
    for (int off = 32; off > 0; off >>= 1) vacc += __shfl_down(vacc, off, 64);
    if ((tid & 63) == 0) wred[tid >> 6] = vacc;

    // ---- f1 scratch (6x66 per img, rows by0/2-1..+4, cols bx0/2-1..+64);
    // interior 4x64 written to global. Clamped taps land on true pixels. ----
    const float wt[4] = {WT0, WT1, WT1, WT0};
    for (int i = tid; i < 2 * 6 * 66; i += 256) {
        const int img = i / 396, j = i % 396;
        const int rr1 = j / 66, cc = j % 66;
        const int r1 = (by0 >> 1) - 1 + rr1;
        const int c1 = (bx0 >> 1) - 1 + cc;
        int sy[4], sx[4];
#pragma unroll
        for (int k = 0; k < 4; ++k) {
            sy[k] = min(max(2 * r1 - 1 + k, 0), 511) - (by0 - 3);
            sx[k] = min(max(2 * c1 - 1 + k, 0), 511) - (bx0 - 4);
        }
        float a = 0.f;
#pragma unroll
        for (int ky = 0; ky < 4; ++ky) {
            const float* row = stg[img][sy[ky]];
            const float rs = WT0 * (row[sx[0]] + row[sx[3]])
                           + WT1 * (row[sx[1]] + row[sx[2]]);
            a = fmaf(wt[ky], rs, a);
        }
        f1b[img][rr1][cc] = a;
        if (rr1 >= 1 && rr1 < 5 && cc >= 1 && cc < 65)
            (img ? h1 : f1)[(size_t)b * 65536 + (size_t)r1 * 256 + c1] = a;
    }
    __syncthreads();

    // ---- f2 build: 2 img x 2 rows x 32 cols = 128 values (tid<128) ----
    if (tid < 128) {
        const int img = tid >> 6, rr2 = (tid >> 5) & 1, cc2 = tid & 31;
        const int y2 = (by0 >> 2) + rr2;
        const int x2 = (bx0 >> 2) + cc2;
        int fr[4], fc[4];
#pragma unroll
        for (int k = 0; k < 4; ++k) {
            fr[k] = min(max(2 * y2 - 1 + k, 0), 255) - ((by0 >> 1) - 1);
            fc[k] = min(max(2 * x2 - 1 + k, 0), 255) - ((bx0 >> 1) - 1);
        }
        float a = 0.f;
#pragma unroll
        for (int ky = 0; ky < 4; ++ky) {
            const float* row = f1b[img][fr[ky]];
            const float rs = WT0 * (row[fc[0]] + row[fc[3]])
                           + WT1 * (row[fc[1]] + row[fc[2]]);
            a = fmaf(wt[ky], rs, a);
        }
        (img ? h2 : f2)[(size_t)b * 16384 + (size_t)y2 * 128 + x2] = a;
    }

    if (tid == 0) {
        const float sB = wred[0] + wred[1] + wred[2] + wred[3];
        const unsigned lin = blockIdx.x + 4u * (blockIdx.y + 64u * blockIdx.z);
        slots[lin] = (double)sB * (double)(1.0f / (8.f * 512.f * 512.f));
    }
}

// ---------------------------------------------------------------------------
// K_B: R16-exact. Tail in one launch (896 blocks), vectorized staging in all
// three flavors.
// ---------------------------------------------------------------------------
__global__ __launch_bounds__(256) void kb_kernel(
    const float* __restrict__ window,
    const float* __restrict__ rw1, const float* __restrict__ rw2,
    const float* __restrict__ rw3,
    const float* __restrict__ f1, const float* __restrict__ h1,
    const float* __restrict__ f2, const float* __restrict__ h2,
    double* __restrict__ slots)
{
    __shared__ __align__(16) float smem[5696];
    __shared__ float swin[25];
    __shared__ float wred[4];

    const int tid = threadIdx.x;
    const int tx = tid & 63, ty = tid >> 6;
    if (tid < 25) swin[tid] = window[tid];
    const int lin = blockIdx.x;

    float v, scale;
    if (lin < 512) {
        // ---- level-1: S=256, tile 256x4, PX=4, float4 rw1; stage origin -4 ----
        constexpr int S = 256, LW = 264;
        const int b = lin >> 6, by0 = (lin & 63) * 4;
        float* sf = smem;
        float* sh = smem + 2112;
        const float* Fb = f1 + (size_t)b * S * S;
        const float* Hb = h1 + (size_t)b * S * S;
        for (int i = tid; i < 2 * 8 * 66; i += 256) {
            const int img = i / 528, j = i % 528;
            const int r = j / 66, c4 = j % 66;
            const int y = by0 - 2 + r, xs = -4 + 4 * c4;
            float4 q = make_float4(0.f, 0.f, 0.f, 0.f);
            if ((unsigned)y < (unsigned)S && (unsigned)xs < (unsigned)S)
                q = *(const float4*)((img ? Hb : Fb) + (size_t)y * S + xs);
            *(float4*)&(img ? sh : sf)[r * LW + 4 * c4] = q;
        }
        __syncthreads();

        const size_t ks = (size_t)S * S;
        const float* rwp = rw1 + (size_t)b * 25 * ks + (size_t)(by0 + ty) * S + 4 * tx;
        float wsum[4] = {0.f,0.f,0.f,0.f}, fs[4] = {0.f,0.f,0.f,0.f}, hs[4] = {0.f,0.f,0.f,0.f};
#pragma unroll
        for (int di = 0; di < 5; ++di) {
            float f12[12], h12[12];
            const int ro = (ty + di) * LW + 4 * tx;
            {
                const float4 a0 = *(const float4*)&sf[ro], a1 = *(const float4*)&sf[ro + 4],
                             a2 = *(const float4*)&sf[ro + 8];
                f12[0]=a0.x; f12[1]=a0.y; f12[2]=a0.z;  f12[3]=a0.w;
                f12[4]=a1.x; f12[5]=a1.y; f12[6]=a1.z;  f12[7]=a1.w;
                f12[8]=a2.x; f12[9]=a2.y; f12[10]=a2.z; f12[11]=a2.w;
                const float4 b0 = *(const float4*)&sh[ro], b1 = *(const float4*)&sh[ro + 4],
                             b2 = *(const float4*)&sh[ro + 8];
                h12[0]=b0.x; h12[1]=b0.y; h12[2]=b0.z;  h12[3]=b0.w;
                h12[4]=b1.x; h12[5]=b1.y; h12[6]=b1.z;  h12[7]=b1.w;
                h12[8]=b2.x; h12[9]=b2.y; h12[10]=b2.z; h12[11]=b2.w;
            }
#pragma unroll
            for (int dj = 0; dj < 5; ++dj) {
                const int k = di * 5 + dj;
                const float4 rv = *(const float4*)(rwp + (size_t)k * ks);
                const float w0 = swin[k] * rv.x, w1 = swin[k] * rv.y;
                const float w2 = swin[k] * rv.z, w3 = swin[k] * rv.w;
                wsum[0] += w0; wsum[1] += w1; wsum[2] += w2; wsum[3] += w3;
                fs[0] = fmaf(w0, f12[dj + 2], fs[0]);
                fs[1] = fmaf(w1, f12[dj + 3], fs[1]);
                fs[2] = fmaf(w2, f12[dj + 4], fs[2]);
                fs[3] = fmaf(w3, f12[dj + 5], fs[3]);
                hs[0] = fmaf(w0, h12[dj + 2], hs[0]);
                hs[1] = fmaf(w1, h12[dj + 3], hs[1]);
                hs[2] = fmaf(w2, h12[dj + 4], hs[2]);
                hs[3] = fmaf(w3, h12[dj + 5], hs[3]);
            }
        }
        v = 0.f;
#pragma unroll
        for (int p = 0; p < 4; ++p) {
            const float d = (fs[p] - hs[p]) / wsum[p];
            v = fmaf(d, d, v);
        }
        scale = 0.5f / (8.f * 256.f * 256.f);
    } else if (lin < 768) {
        // ---- level-2: S=128, tile 128x4, PX=2, float2 rw2; stage origin -4 ----
        constexpr int S = 128, LW = 136;
        const int t = lin - 512;
        const int b = t >> 5, by0 = (t & 31) * 4;
        float* sf = smem;
        float* sh = smem + 1088;
        const float* Fb = f2 + (size_t)b * S * S;
        const float* Hb = h2 + (size_t)b * S * S;
        for (int i = tid; i < 2 * 8 * 34; i += 256) {
            const int img = i / 272, j = i % 272;
            const int r = j / 34, c4 = j % 34;
            const int y = by0 - 2 + r, xs = -4 + 4 * c4;
            float4 q = make_float4(0.f, 0.f, 0.f, 0.f);
            if ((unsigned)y < (unsigned)S && (unsigned)xs < (unsigned)S)
                q = *(const float4*)((img ? Hb : Fb) + (size_t)y * S + xs);
            *(float4*)&(img ? sh : sf)[r * LW + 4 * c4] = q;
        }
        __syncthreads();

        const size_t ks = (size_t)S * S;
        const float* rwp = rw2 + (size_t)b * 25 * ks + (size_t)(by0 + ty) * S + 2 * tx;
        float wsum[2] = {0.f,0.f}, fs[2] = {0.f,0.f}, hs[2] = {0.f,0.f};
#pragma unroll
        for (int di = 0; di < 5; ++di) {
            float f7[8], h7[8];
            const int ro = (ty + di) * LW + 2 * tx + 2;
#pragma unroll
            for (int q2 = 0; q2 < 4; ++q2) {
                const float2 af = *(const float2*)&sf[ro + 2 * q2];
                f7[2 * q2] = af.x; f7[2 * q2 + 1] = af.y;
                const float2 ah = *(const float2*)&sh[ro + 2 * q2];
                h7[2 * q2] = ah.x; h7[2 * q2 + 1] = ah.y;
            }
#pragma unroll
            for (int dj = 0; dj < 5; ++dj) {
                const int k = di * 5 + dj;
                const float2 rv = *(const float2*)(rwp + (size_t)k * ks);
                const float w0 = swin[k] * rv.x, w1 = swin[k] * rv.y;
                wsum[0] += w0; wsum[1] += w1;
                fs[0] = fmaf(w0, f7[dj + 0], fs[0]);
                fs[1] = fmaf(w1, f7[dj + 1], fs[1]);
                hs[0] = fmaf(w0, h7[dj + 0], hs[0]);
                hs[1] = fmaf(w1, h7[dj + 1], hs[1]);
            }
        }
        const float d0 = (fs[0] - hs[0]) / wsum[0];
        const float d1 = (fs[1] - hs[1]) / wsum[1];
        v = fmaf(d0, d0, d1 * d1);
        scale = 0.25f / (8.f * 128.f * 128.f);
    } else {
        // ---- level-3: S=64, rebuild L3 tile locally from f2/h2 ----
        const int t = lin - 768;
        const int b = t >> 4, by0 = (t & 15) * 4;
        float* p2 = smem;          // [2][18][128]
        float* l3 = smem + 4608;   // [2][8][68]
        const int fr0 = 2 * by0 - 5;
        for (int i = tid; i < 2 * 18 * 32; i += 256) {
            const int img = i / 576, j = i % 576;
            const int r = j >> 5, c4 = j & 31;
            const int gy = min(max(fr0 + r, 0), 127);
            const float4 q = *(const float4*)((img ? h2 : f2)
                              + ((size_t)b * 128 + gy) * 128 + 4 * c4);
            *(float4*)&p2[img * 2304 + r * 128 + 4 * c4] = q;
        }
        __syncthreads();
        const float wt[4] = {WT0, WT1, WT1, WT0};
        for (int i = tid; i < 2 * 8 * 68; i += 256) {
            const int img = i / 544, j = i % 544;
            const int r = j / 68, c = j % 68;
            const int gy = by0 - 2 + r, gx = c - 2;
            float a = 0.f;
            if ((unsigned)gy < 64u && (unsigned)gx < 64u) {
                int ry[4], cx[4];
#pragma unroll
                for (int k = 0; k < 4; ++k) {
                    ry[k] = min(max(2 * gy - 1 + k, 0), 127) - fr0;
                    cx[k] = min(max(2 * gx - 1 + k, 0), 127);
                }
#pragma unroll
                for (int ky = 0; ky < 4; ++ky) {
                    const float* row = p2 + img * 2304 + ry[ky] * 128;
                    const float rs = WT0 * (row[cx[0]] + row[cx[3]])
                                   + WT1 * (row[cx[1]] + row[cx[2]]);
                    a = fmaf(wt[ky], rs, a);
                }
            }
            l3[i] = a;
        }
        __syncthreads();

        const size_t ks = 64 * 64;
        const float* rwp = rw3 + (size_t)b * 25 * ks + (size_t)(by0 + ty) * 64 + tx;
        float wsum = 0.f, fsv = 0.f, hsv = 0.f;
#pragma unroll
        for (int di = 0; di < 5; ++di) {
#pragma unroll
            for (int dj = 0; dj < 5; ++dj) {
                const int k = di * 5 + dj;
                const float wm = swin[k] * rwp[(size_t)k * ks];
                wsum += wm;
                fsv = fmaf(wm, l3[0 * 544 + (ty + di) * 68 + (tx + dj)], fsv);
                hsv = fmaf(wm, l3[1 * 544 + (ty + di) * 68 + (tx + dj)], hsv);
            }
        }
        const float d = (fsv - hsv) / wsum;
        v = d * d;
        scale = 0.125f / (8.f * 64.f * 64.f);
    }

#pragma unroll
    for (int off = 32; off > 0; off >>= 1) v += __shfl_down(v, off, 64);
    if ((tid & 63) == 0) wred[tid >> 6] = v;
    __syncthreads();
    if (tid == 0) {
        const float sB = wred[0] + wred[1] + wred[2] + wred[3];
        slots[lin] = (double)sB * (double)scale;
    }
}

__global__ void finalize_kernel(const double* __restrict__ slots, float* __restrict__ out, int n)
{
    __shared__ double dred[4];
    const int t = threadIdx.x;  // 256 threads
    double s = 0.0;
    for (int i = t; i < n; i += 256) s += slots[i];
#pragma unroll
    for (int off = 32; off > 0; off >>= 1) s += __shfl_down(s, off, 64);
    if ((t & 63) == 0) dred[t >> 6] = s;
    __syncthreads();
    if (t == 0) out[0] = (float)(dred[0] + dred[1] + dred[2] + dred[3]);
}

extern "C" void kernel_launch(void* const* d_in, const int* in_sizes, int n_in,
                              void* d_out, int out_size, void* d_ws, size_t ws_size,
                              hipStream_t stream)
{
    const float* fake   = (const float*)d_in[0];
    const float* hdr    = (const float*)d_in[1];
    const float* window = (const float*)d_in[2];
    const float* rw0    = (const float*)d_in[3];
    const float* rw1    = (const float*)d_in[4];
    const float* rw2    = (const float*)d_in[5];
    const float* rw3    = (const float*)d_in[6];
    float* out = (float*)d_out;

    const int B = 8;
    char* ws = (char*)d_ws;
    double* slots = (double*)ws;                 // 2944 doubles, all stored each call
    float* f1 = (float*)(ws + 32768);
    const size_t n1 = (size_t)B * 256 * 256;
    float* h1 = f1 + n1;
    float* f2 = h1 + n1;
    const size_t n2 = (size_t)B * 128 * 128;
    float* h2 = f2 + n2;

    // K1: level-0 loss + f1 + f2 build. 2048 blocks (tile 128x8, PX=2, 18KB LDS).
    k1_kernel<<<dim3(4, 64, B), 256, 0, stream>>>(
        fake, hdr, window, rw0, slots, f1, h1, f2, h2);

    // K_B: levels 1+2+3 in one launch (512+256+128 = 896 blocks).
    kb_kernel<<<dim3(896), 256, 0, stream>>>(
        window, rw1, rw2, rw3, f1, h1, f2, h2, slots + 2048);

    // finalize: 2944 slots.
    finalize_kernel<<<1, 256, 0, stream>>>(slots, out, 2944);
}

// Round 18
// 62.349 us; speedup vs baseline: 1.0133x; 1.0133x over previous
//
#include <hip/hip_runtime.h>
#include <hip/hip_bf16.h>

#define WT0 (-0.09375f)
#define WT1 (0.59375f)

// ---------------------------------------------------------------------------
// K1: R16-exact (best known, 61.5us). Level-0 loss (tile 256x8, 2 rows x
// 4 px/thread, float4 rw0 loads) + cascade f1 + f2 build, float4 staging.
// R17's PX=2 variant regressed (63.2): rw-load issue count doubled and VGPR
// didn't cross the 64 boundary — float4 16B/lane is the right shape here.
// ---------------------------------------------------------------------------
__global__ __launch_bounds__(256) void k1_kernel(
    const float* __restrict__ fake, const float* __restrict__ hdr,
    const float* __restrict__ window, const float* __restrict__ RW,
    double* __restrict__ slots,
    float* __restrict__ f1, float* __restrict__ h1,
    float* __restrict__ f2, float* __restrict__ h2)
{
    __shared__ __align__(16) float stg[2][16][264];
    __shared__ float f1b[2][6][130];
    __shared__ float swin[25];
    __shared__ float wred[4];

    const int tid = threadIdx.x;
    const int tx = tid & 63, ty = tid >> 6;
    if (tid < 25) swin[tid] = window[tid];

    const int bx0 = blockIdx.x * 256;
    const int by0 = blockIdx.y * 8;
    const int b   = blockIdx.z;

    const float* Fb = fake + (size_t)b * 512 * 512;
    const float* Hb = hdr  + (size_t)b * 512 * 512;

    // stage 16x264 per image as float4 quads, zero-pad outside [0,512)^2
    for (int i = tid; i < 2 * 16 * 66; i += 256) {
        const int img = i / 1056, j = i % 1056;
        const int r = j / 66, c4 = j % 66;
        const int y = by0 - 4 + r, xs = bx0 - 4 + 4 * c4;
        float4 v = make_float4(0.f, 0.f, 0.f, 0.f);
        if ((unsigned)y < 512u && (unsigned)xs < 512u)
            v = *(const float4*)((img ? Hb : Fb) + (size_t)y * 512 + xs);
        *(float4*)&stg[img][r][4 * c4] = v;
    }
    __syncthreads();

    // ---- loss: rows (by0+ty) and (by0+ty+4), 4 px each ----
    float vacc = 0.f;
    const size_t ks = (size_t)512 * 512;
#pragma unroll
    for (int rr = 0; rr < 2; ++rr) {
        const int y = by0 + ty + 4 * rr;
        const float* rwp = RW + (size_t)b * 25 * ks + (size_t)y * 512 + (bx0 + 4 * tx);
        float wsum[4] = {0.f,0.f,0.f,0.f}, fs[4] = {0.f,0.f,0.f,0.f}, hs[4] = {0.f,0.f,0.f,0.f};
#pragma unroll
        for (int di = 0; di < 5; ++di) {
            const int srow = ty + 4 * rr + di + 2;     // image row y+di-2
            float f12[12], h12[12];
            {
                const float4* pf = (const float4*)&stg[0][srow][4 * tx];
                const float4 a0 = pf[0], a1 = pf[1], a2 = pf[2];
                f12[0]=a0.x; f12[1]=a0.y; f12[2]=a0.z;  f12[3]=a0.w;
                f12[4]=a1.x; f12[5]=a1.y; f12[6]=a1.z;  f12[7]=a1.w;
                f12[8]=a2.x; f12[9]=a2.y; f12[10]=a2.z; f12[11]=a2.w;
                const float4* ph = (const float4*)&stg[1][srow][4 * tx];
                const float4 b0 = ph[0], b1 = ph[1], b2 = ph[2];
                h12[0]=b0.x; h12[1]=b0.y; h12[2]=b0.z;  h12[3]=b0.w;
                h12[4]=b1.x; h12[5]=b1.y; h12[6]=b1.z;  h12[7]=b1.w;
                h12[8]=b2.x; h12[9]=b2.y; h12[10]=b2.z; h12[11]=b2.w;
            }
#pragma unroll
            for (int dj = 0; dj < 5; ++dj) {
                const int k = di * 5 + dj;
                const float4 rv = *(const float4*)(rwp + (size_t)k * ks);
                const float w0 = swin[k] * rv.x, w1 = swin[k] * rv.y;
                const float w2 = swin[k] * rv.z, w3 = swin[k] * rv.w;
                wsum[0] += w0; wsum[1] += w1; wsum[2] += w2; wsum[3] += w3;
                fs[0] = fmaf(w0, f12[dj + 2], fs[0]);
                fs[1] = fmaf(w1, f12[dj + 3], fs[1]);
                fs[2] = fmaf(w2, f12[dj + 4], fs[2]);
                fs[3] = fmaf(w3, f12[dj + 5], fs[3]);
                hs[0] = fmaf(w0, h12[dj + 2], hs[0]);
                hs[1] = fmaf(w1, h12[dj + 3], hs[1]);
                hs[2] = fmaf(w2, h12[dj + 4], hs[2]);
                hs[3] = fmaf(w3, h12[dj + 5], hs[3]);
            }
        }
#pragma unroll
        for (int p = 0; p < 4; ++p) {
            const float d = (fs[p] - hs[p]) / wsum[p];
            vacc = fmaf(d, d, vacc);
        }
    }
#pragma unroll
    for (int off = 32; off > 0; off >>= 1) vacc += __shfl_down(vacc, off, 64);
    if ((tid & 63) == 0) wred[tid >> 6] = vacc;

    // ---- f1 build ----
    const float wt[4] = {WT0, WT1, WT1, WT0};
    for (int i = tid; i < 2 * 6 * 130; i += 256) {
        const int img = i / 780, j = i % 780;
        const int rr = j / 130, cc = j % 130;
        const int r1 = (by0 >> 1) - 1 + rr;
        const int c1 = (bx0 >> 1) - 1 + cc;
        int sy[4], sx[4];
#pragma unroll
        for (int k = 0; k < 4; ++k) {
            sy[k] = min(max(2 * r1 - 1 + k, 0), 511) - (by0 - 4);
            sx[k] = min(max(2 * c1 - 1 + k, 0), 511) - (bx0 - 4);
        }
        float a = 0.f;
#pragma unroll
        for (int ky = 0; ky < 4; ++ky) {
            const float* row = stg[img][sy[ky]];
            const float rs = WT0 * (row[sx[0]] + row[sx[3]])
                           + WT1 * (row[sx[1]] + row[sx[2]]);
            a = fmaf(wt[ky], rs, a);
        }
        f1b[img][rr][cc] = a;
        if (rr >= 1 && rr < 5 && cc >= 1 && cc < 129)
            (img ? h1 : f1)[(size_t)b * 65536 + (size_t)r1 * 256 + c1] = a;
    }
    __syncthreads();

    // ---- f2 build ----
    {
        const int img = tid >> 7, j = tid & 127;
        const int rr2 = j >> 6, cc2 = j & 63;
        const int y2 = (by0 >> 2) + rr2;
        const int x2 = (bx0 >> 2) + cc2;
        int fr[4], fc[4];
#pragma unroll
        for (int k = 0; k < 4; ++k) {
            fr[k] = min(max(2 * y2 - 1 + k, 0), 255) - ((by0 >> 1) - 1);
            fc[k] = min(max(2 * x2 - 1 + k, 0), 255) - ((bx0 >> 1) - 1);
        }
        float a = 0.f;
#pragma unroll
        for (int ky = 0; ky < 4; ++ky) {
            const float* row = f1b[img][fr[ky]];
            const float rs = WT0 * (row[fc[0]] + row[fc[3]])
                           + WT1 * (row[fc[1]] + row[fc[2]]);
            a = fmaf(wt[ky], rs, a);
        }
        (img ? h2 : f2)[(size_t)b * 16384 + (size_t)y2 * 128 + x2] = a;
    }

    if (tid == 0) {
        const float sB = wred[0] + wred[1] + wred[2] + wred[3];
        const unsigned lin = blockIdx.x + 2u * (blockIdx.y + 64u * blockIdx.z);
        slots[lin] = (double)sB * (double)(1.0f / (8.f * 512.f * 512.f));
    }
}

// ---------------------------------------------------------------------------
// K_B: R16-exact. Tail in one launch (896 blocks), vectorized staging in all
// three flavors (quad-aligned, origin -4, per-quad zero-pad predicate).
// ---------------------------------------------------------------------------
__global__ __launch_bounds__(256) void kb_kernel(
    const float* __restrict__ window,
    const float* __restrict__ rw1, const float* __restrict__ rw2,
    const float* __restrict__ rw3,
    const float* __restrict__ f1, const float* __restrict__ h1,
    const float* __restrict__ f2, const float* __restrict__ h2,
    double* __restrict__ slots)
{
    __shared__ __align__(16) float smem[5696];
    __shared__ float swin[25];
    __shared__ float wred[4];

    const int tid = threadIdx.x;
    const int tx = tid & 63, ty = tid >> 6;
    if (tid < 25) swin[tid] = window[tid];
    const int lin = blockIdx.x;

    float v, scale;
    if (lin < 512) {
        // ---- level-1: S=256, tile 256x4, PX=4, float4 rw1; stage origin -4 ----
        constexpr int S = 256, LW = 264;
        const int b = lin >> 6, by0 = (lin & 63) * 4;
        float* sf = smem;
        float* sh = smem + 2112;
        const float* Fb = f1 + (size_t)b * S * S;
        const float* Hb = h1 + (size_t)b * S * S;
        for (int i = tid; i < 2 * 8 * 66; i += 256) {
            const int img = i / 528, j = i % 528;
            const int r = j / 66, c4 = j % 66;
            const int y = by0 - 2 + r, xs = -4 + 4 * c4;
            float4 q = make_float4(0.f, 0.f, 0.f, 0.f);
            if ((unsigned)y < (unsigned)S && (unsigned)xs < (unsigned)S)
                q = *(const float4*)((img ? Hb : Fb) + (size_t)y * S + xs);
            *(float4*)&(img ? sh : sf)[r * LW + 4 * c4] = q;
        }
        __syncthreads();

        const size_t ks = (size_t)S * S;
        const float* rwp = rw1 + (size_t)b * 25 * ks + (size_t)(by0 + ty) * S + 4 * tx;
        float wsum[4] = {0.f,0.f,0.f,0.f}, fs[4] = {0.f,0.f,0.f,0.f}, hs[4] = {0.f,0.f,0.f,0.f};
#pragma unroll
        for (int di = 0; di < 5; ++di) {
            float f12[12], h12[12];
            const int ro = (ty + di) * LW + 4 * tx;
            {
                const float4 a0 = *(const float4*)&sf[ro], a1 = *(const float4*)&sf[ro + 4],
                             a2 = *(const float4*)&sf[ro + 8];
                f12[0]=a0.x; f12[1]=a0.y; f12[2]=a0.z;  f12[3]=a0.w;
                f12[4]=a1.x; f12[5]=a1.y; f12[6]=a1.z;  f12[7]=a1.w;
                f12[8]=a2.x; f12[9]=a2.y; f12[10]=a2.z; f12[11]=a2.w;
                const float4 b0 = *(const float4*)&sh[ro], b1 = *(const float4*)&sh[ro + 4],
                             b2 = *(const float4*)&sh[ro + 8];
                h12[0]=b0.x; h12[1]=b0.y; h12[2]=b0.z;  h12[3]=b0.w;
                h12[4]=b1.x; h12[5]=b1.y; h12[6]=b1.z;  h12[7]=b1.w;
                h12[8]=b2.x; h12[9]=b2.y; h12[10]=b2.z; h12[11]=b2.w;
            }
#pragma unroll
            for (int dj = 0; dj < 5; ++dj) {
                const int k = di * 5 + dj;
                const float4 rv = *(const float4*)(rwp + (size_t)k * ks);
                const float w0 = swin[k] * rv.x, w1 = swin[k] * rv.y;
                const float w2 = swin[k] * rv.z, w3 = swin[k] * rv.w;
                wsum[0] += w0; wsum[1] += w1; wsum[2] += w2; wsum[3] += w3;
                fs[0] = fmaf(w0, f12[dj + 2], fs[0]);
                fs[1] = fmaf(w1, f12[dj + 3], fs[1]);
                fs[2] = fmaf(w2, f12[dj + 4], fs[2]);
                fs[3] = fmaf(w3, f12[dj + 5], fs[3]);
                hs[0] = fmaf(w0, h12[dj + 2], hs[0]);
                hs[1] = fmaf(w1, h12[dj + 3], hs[1]);
                hs[2] = fmaf(w2, h12[dj + 4], hs[2]);
                hs[3] = fmaf(w3, h12[dj + 5], hs[3]);
            }
        }
        v = 0.f;
#pragma unroll
        for (int p = 0; p < 4; ++p) {
            const float d = (fs[p] - hs[p]) / wsum[p];
            v = fmaf(d, d, v);
        }
        scale = 0.5f / (8.f * 256.f * 256.f);
    } else if (lin < 768) {
        // ---- level-2: S=128, tile 128x4, PX=2, float2 rw2; stage origin -4 ----
        constexpr int S = 128, LW = 136;
        const int t = lin - 512;
        const int b = t >> 5, by0 = (t & 31) * 4;
        float* sf = smem;
        float* sh = smem + 1088;
        const float* Fb = f2 + (size_t)b * S * S;
        const float* Hb = h2 + (size_t)b * S * S;
        for (int i = tid; i < 2 * 8 * 34; i += 256) {
            const int img = i / 272, j = i % 272;
            const int r = j / 34, c4 = j % 34;
            const int y = by0 - 2 + r, xs = -4 + 4 * c4;
            float4 q = make_float4(0.f, 0.f, 0.f, 0.f);
            if ((unsigned)y < (unsigned)S && (unsigned)xs < (unsigned)S)
                q = *(const float4*)((img ? Hb : Fb) + (size_t)y * S + xs);
            *(float4*)&(img ? sh : sf)[r * LW + 4 * c4] = q;
        }
        __syncthreads();

        const size_t ks = (size_t)S * S;
        const float* rwp = rw2 + (size_t)b * 25 * ks + (size_t)(by0 + ty) * S + 2 * tx;
        float wsum[2] = {0.f,0.f}, fs[2] = {0.f,0.f}, hs[2] = {0.f,0.f};
#pragma unroll
        for (int di = 0; di < 5; ++di) {
            float f7[8], h7[8];
            const int ro = (ty + di) * LW + 2 * tx + 2;
#pragma unroll
            for (int q2 = 0; q2 < 4; ++q2) {
                const float2 af = *(const float2*)&sf[ro + 2 * q2];
                f7[2 * q2] = af.x; f7[2 * q2 + 1] = af.y;
                const float2 ah = *(const float2*)&sh[ro + 2 * q2];
                h7[2 * q2] = ah.x; h7[2 * q2 + 1] = ah.y;
            }
#pragma unroll
            for (int dj = 0; dj < 5; ++dj) {
                const int k = di * 5 + dj;
                const float2 rv = *(const float2*)(rwp + (size_t)k * ks);
                const float w0 = swin[k] * rv.x, w1 = swin[k] * rv.y;
                wsum[0] += w0; wsum[1] += w1;
                fs[0] = fmaf(w0, f7[dj + 0], fs[0]);
                fs[1] = fmaf(w1, f7[dj + 1], fs[1]);
                hs[0] = fmaf(w0, h7[dj + 0], hs[0]);
                hs[1] = fmaf(w1, h7[dj + 1], hs[1]);
            }
        }
        const float d0 = (fs[0] - hs[0]) / wsum[0];
        const float d1 = (fs[1] - hs[1]) / wsum[1];
        v = fmaf(d0, d0, d1 * d1);
        scale = 0.25f / (8.f * 128.f * 128.f);
    } else {
        // ---- level-3: S=64, rebuild L3 tile locally from f2/h2 ----
        const int t = lin - 768;
        const int b = t >> 4, by0 = (t & 15) * 4;
        float* p2 = smem;          // [2][18][128]
        float* l3 = smem + 4608;   // [2][8][68]
        const int fr0 = 2 * by0 - 5;
        for (int i = tid; i < 2 * 18 * 32; i += 256) {
            const int img = i / 576, j = i % 576;
            const int r = j >> 5, c4 = j & 31;
            const int gy = min(max(fr0 + r, 0), 127);
            const float4 q = *(const float4*)((img ? h2 : f2)
                              + ((size_t)b * 128 + gy) * 128 + 4 * c4);
            *(float4*)&p2[img * 2304 + r * 128 + 4 * c4] = q;
        }
        __syncthreads();
        const float wt[4] = {WT0, WT1, WT1, WT0};
        for (int i = tid; i < 2 * 8 * 68; i += 256) {
            const int img = i / 544, j = i % 544;
            const int r = j / 68, c = j % 68;
            const int gy = by0 - 2 + r, gx = c - 2;
            float a = 0.f;
            if ((unsigned)gy < 64u && (unsigned)gx < 64u) {
                int ry[4], cx[4];
#pragma unroll
                for (int k = 0; k < 4; ++k) {
                    ry[k] = min(max(2 * gy - 1 + k, 0), 127) - fr0;
                    cx[k] = min(max(2 * gx - 1 + k, 0), 127);
                }
#pragma unroll
                for (int ky = 0; ky < 4; ++ky) {
                    const float* row = p2 + img * 2304 + ry[ky] * 128;
                    const float rs = WT0 * (row[cx[0]] + row[cx[3]])
                                   + WT1 * (row[cx[1]] + row[cx[2]]);
                    a = fmaf(wt[ky], rs, a);
                }
            }
            l3[i] = a;
        }
        __syncthreads();

        const size_t ks = 64 * 64;
        const float* rwp = rw3 + (size_t)b * 25 * ks + (size_t)(by0 + ty) * 64 + tx;
        float wsum = 0.f, fsv = 0.f, hsv = 0.f;
#pragma unroll
        for (int di = 0; di < 5; ++di) {
#pragma unroll
            for (int dj = 0; dj < 5; ++dj) {
                const int k = di * 5 + dj;
                const float wm = swin[k] * rwp[(size_t)k * ks];
                wsum += wm;
                fsv = fmaf(wm, l3[0 * 544 + (ty + di) * 68 + (tx + dj)], fsv);
                hsv = fmaf(wm, l3[1 * 544 + (ty + di) * 68 + (tx + dj)], hsv);
            }
        }
        const float d = (fsv - hsv) / wsum;
        v = d * d;
        scale = 0.125f / (8.f * 64.f * 64.f);
    }

#pragma unroll
    for (int off = 32; off > 0; off >>= 1) v += __shfl_down(v, off, 64);
    if ((tid & 63) == 0) wred[tid >> 6] = v;
    __syncthreads();
    if (tid == 0) {
        const float sB = wred[0] + wred[1] + wred[2] + wred[3];
        slots[lin] = (double)sB * (double)scale;
    }
}

__global__ void finalize_kernel(const double* __restrict__ slots, float* __restrict__ out, int n)
{
    __shared__ double dred[4];
    const int t = threadIdx.x;  // 256 threads
    double s = 0.0;
    for (int i = t; i < n; i += 256) s += slots[i];
#pragma unroll
    for (int off = 32; off > 0; off >>= 1) s += __shfl_down(s, off, 64);
    if ((t & 63) == 0) dred[t >> 6] = s;
    __syncthreads();
    if (t == 0) out[0] = (float)(dred[0] + dred[1] + dred[2] + dred[3]);
}

extern "C" void kernel_launch(void* const* d_in, const int* in_sizes, int n_in,
                              void* d_out, int out_size, void* d_ws, size_t ws_size,
                              hipStream_t stream)
{
    const float* fake   = (const float*)d_in[0];
    const float* hdr    = (const float*)d_in[1];
    const float* window = (const float*)d_in[2];
    const float* rw0    = (const float*)d_in[3];
    const float* rw1    = (const float*)d_in[4];
    const float* rw2    = (const float*)d_in[5];
    const float* rw3    = (const float*)d_in[6];
    float* out = (float*)d_out;

    const int B = 8;
    char* ws = (char*)d_ws;
    double* slots = (double*)ws;                 // 1920 doubles, all stored each call
    float* f1 = (float*)(ws + 32768);
    const size_t n1 = (size_t)B * 256 * 256;
    float* h1 = f1 + n1;
    float* f2 = h1 + n1;
    const size_t n2 = (size_t)B * 128 * 128;
    float* h2 = f2 + n2;

    // K1: level-0 loss + f1 + f2 build. 1024 blocks.
    k1_kernel<<<dim3(2, 64, B), 256, 0, stream>>>(
        fake, hdr, window, rw0, slots, f1, h1, f2, h2);

    // K_B: levels 1+2+3 in one launch (512+256+128 = 896 blocks).
    kb_kernel<<<dim3(896), 256, 0, stream>>>(
        window, rw1, rw2, rw3, f1, h1, f2, h2, slots + 1024);

    // finalize: 1920 slots.
    finalize_kernel<<<1, 256, 0, stream>>>(slots, out, 1920);
}